// Round 1
// baseline (473.160 us; speedup 1.0000x reference)
//
#include <hip/hip_runtime.h>
#include <math.h>

// Problem constants
#define BB 4
#define CIN 64
#define COUT 64
#define HH 128
#define WW 128
#define KK 9
#define HW (HH*WW)

// ---------------------------------------------------------------------------
// K1: fvec[b][j] = sum_i c1_w[j][i] * fea[b][i]   (j indexes the 64 vals that
//     scale along CIN);  bias2[o2] = sum_o c2_w[o2][o]*bias[o]
// ---------------------------------------------------------------------------
__global__ void prep_kernel(const float* __restrict__ c1w,
                            const float* __restrict__ fea,
                            const float* __restrict__ c2w,
                            const float* __restrict__ bias,
                            float* __restrict__ fvec,
                            float* __restrict__ bias2) {
    int t = threadIdx.x;            // 0..255
    int b = t >> 6, c = t & 63;
    float s = 0.f;
    for (int i = 0; i < 4*CIN; ++i) s += c1w[c*(4*CIN) + i] * fea[b*(4*CIN) + i];
    fvec[t] = s;
    if (t < COUT) {
        float s2 = 0.f;
        for (int o = 0; o < COUT; ++o) s2 += c2w[t*COUT + o] * bias[o];
        bias2[t] = s2;
    }
}

// ---------------------------------------------------------------------------
// K2: W2[b][p][c][o2] = fvec[b][c] * sum_o c2_w[o2][o] * weight[o][c][p]
//     index = ((b*9 + p)*64 + c)*64 + o2
// ---------------------------------------------------------------------------
__global__ void w2_kernel(const float* __restrict__ weight,
                          const float* __restrict__ c2w,
                          const float* __restrict__ fvec,
                          float* __restrict__ w2) {
    int t = blockIdx.x * 256 + threadIdx.x;     // < 4*9*64*64 = 147456
    int o2 = t & 63;
    int c  = (t >> 6) & 63;
    int bp = t >> 12;           // b*9 + p
    int p  = bp % 9;
    int b  = bp / 9;
    float s = 0.f;
    for (int o = 0; o < COUT; ++o)
        s += c2w[o2*COUT + o] * weight[(o*CIN + c)*KK + p];
    w2[t] = s * fvec[b*CIN + c];
}

// ---------------------------------------------------------------------------
// K3: offset conv.  om[b][ch][pix] = sum_{c,k} com_w[ch][c][k]*inter_nb + com_b
//     ch: 2p -> dy, 2p+1 -> dx, 18+p -> mask logit.
//     Emits absolute coords ys,xs and sigmoid(mask).
//     Block = 256 threads = 16x16 pixel tile.  Grid (8,8,4).
// ---------------------------------------------------------------------------
__global__ __launch_bounds__(256) void conv_off_kernel(
        const float* __restrict__ inter,
        const float* __restrict__ com_w,
        const float* __restrict__ com_b,
        float* __restrict__ ys, float* __restrict__ xs, float* __restrict__ mk) {
    __shared__ float wls[32*9*28];   // [c_local][k][oc padded to 28]
    int b  = blockIdx.z;
    int x  = blockIdx.x*16 + (threadIdx.x & 15);
    int y  = blockIdx.y*16 + (threadIdx.x >> 4);

    float acc[28];
    #pragma unroll
    for (int i = 0; i < 28; ++i) acc[i] = 0.f;

    for (int cc = 0; cc < CIN; cc += 32) {
        __syncthreads();
        for (int i = threadIdx.x; i < 27*288; i += 256) {
            int oc = i / 288; int rem = i % 288;
            int cl = rem / 9; int k = rem % 9;
            wls[(cl*9 + k)*28 + oc] = com_w[oc*(CIN*KK) + (cc+cl)*9 + k];
        }
        for (int i = threadIdx.x; i < 288; i += 256) wls[i*28 + 27] = 0.f;
        __syncthreads();

        const float* I = inter + (b*CIN + cc)*HW;
        for (int cl = 0; cl < 32; ++cl) {
            #pragma unroll
            for (int ky = 0; ky < 3; ++ky) {
                int yy = y + ky - 1;
                bool vy = (yy >= 0) && (yy < HH);
                #pragma unroll
                for (int kx = 0; kx < 3; ++kx) {
                    int xx = x + kx - 1;
                    float v = (vy && xx >= 0 && xx < WW) ? I[yy*WW + xx] : 0.f;
                    const float4* wrow = (const float4*)(wls + (cl*9 + ky*3 + kx)*28);
                    #pragma unroll
                    for (int og = 0; og < 7; ++og) {
                        float4 wv = wrow[og];
                        acc[og*4+0] += wv.x * v;
                        acc[og*4+1] += wv.y * v;
                        acc[og*4+2] += wv.z * v;
                        acc[og*4+3] += wv.w * v;
                    }
                }
            }
            I += HW;
        }
    }

    int pix = y*WW + x;
    #pragma unroll
    for (int p = 0; p < 9; ++p) {
        float dy = acc[2*p]   + com_b[2*p];
        float dx = acc[2*p+1] + com_b[2*p+1];
        float ml = acc[18+p]  + com_b[18+p];
        float m  = 1.f / (1.f + expf(-ml));
        int o = (b*9 + p)*HW + pix;
        ys[o] = (float)(y - 1 + p/3) + dy;
        xs[o] = (float)(x - 1 + p%3) + dx;
        mk[o] = m;
    }
}

// ---------------------------------------------------------------------------
// K4: main DCN GEMM.  final[b][o2][pix] = sum_{p,c} W2[b][p][c][o2] * val + bias2
//     val = bilinear(input_feat[b][c], ys,xs) * mask  (mask folded into corner wts)
//     Block = 256 threads = 16x16 pixel tile, 64 accumulators/thread.
// ---------------------------------------------------------------------------
__global__ __launch_bounds__(256) void dcn_main_kernel(
        const float* __restrict__ input_feat,
        const float* __restrict__ w2,
        const float* __restrict__ bias2,
        const float* __restrict__ ys, const float* __restrict__ xs,
        const float* __restrict__ mk,
        float* __restrict__ out) {
    __shared__ float w2s[64*64];     // [c][o2] for current p
    int b  = blockIdx.z;
    int x  = blockIdx.x*16 + (threadIdx.x & 15);
    int y  = blockIdx.y*16 + (threadIdx.x >> 4);
    int pix = y*WW + x;
    const float* F = input_feat + b*CIN*HW;

    float acc[64];
    #pragma unroll
    for (int o = 0; o < 64; ++o) acc[o] = bias2[o];

    for (int p = 0; p < 9; ++p) {
        __syncthreads();
        {
            const float4* src = (const float4*)(w2 + (size_t)((b*9 + p)*64)*64);
            float4* dst = (float4*)w2s;
            for (int i = threadIdx.x; i < 1024; i += 256) dst[i] = src[i];
        }
        __syncthreads();

        int ip = (b*9 + p)*HW + pix;
        float ysv = ys[ip], xsv = xs[ip], mv = mk[ip];
        float y0f = floorf(ysv), x0f = floorf(xsv);
        float ly = ysv - y0f, lx = xsv - x0f;
        int y0 = (int)y0f, x0 = (int)x0f;
        int y1 = y0 + 1, x1 = x0 + 1;
        float vy0 = (y0 >= 0 && y0 < HH) ? 1.f : 0.f;
        float vy1 = (y1 >= 0 && y1 < HH) ? 1.f : 0.f;
        float vx0 = (x0 >= 0 && x0 < WW) ? 1.f : 0.f;
        float vx1 = (x1 >= 0 && x1 < WW) ? 1.f : 0.f;
        float w00 = (1.f-ly)*(1.f-lx)*mv * vy0*vx0;
        float w01 = (1.f-ly)*lx      *mv * vy0*vx1;
        float w10 = ly      *(1.f-lx)*mv * vy1*vx0;
        float w11 = ly      *lx      *mv * vy1*vx1;
        int y0c = min(max(y0,0),HH-1), y1c = min(max(y1,0),HH-1);
        int x0c = min(max(x0,0),WW-1), x1c = min(max(x1,0),WW-1);
        int i00 = y0c*WW + x0c, i01 = y0c*WW + x1c;
        int i10 = y1c*WW + x0c, i11 = y1c*WW + x1c;

        const float* Fc = F;
        for (int c = 0; c < CIN; ++c) {
            float v = w00*Fc[i00] + w01*Fc[i01] + w10*Fc[i10] + w11*Fc[i11];
            const float4* wrow = (const float4*)(w2s + c*64);
            #pragma unroll
            for (int og = 0; og < 16; ++og) {
                float4 wv = wrow[og];
                acc[og*4+0] += wv.x * v;
                acc[og*4+1] += wv.y * v;
                acc[og*4+2] += wv.z * v;
                acc[og*4+3] += wv.w * v;
            }
            Fc += HW;
        }
    }

    float* outp = out + (size_t)b*COUT*HW + pix;
    #pragma unroll
    for (int o = 0; o < 64; ++o) outp[o*HW] = acc[o];
}

// ---------------------------------------------------------------------------
extern "C" void kernel_launch(void* const* d_in, const int* in_sizes, int n_in,
                              void* d_out, int out_size, void* d_ws, size_t ws_size,
                              hipStream_t stream) {
    const float* input_feat = (const float*)d_in[0];
    const float* inter      = (const float*)d_in[1];
    const float* fea        = (const float*)d_in[2];
    const float* weight     = (const float*)d_in[3];
    const float* bias       = (const float*)d_in[4];
    const float* com_w      = (const float*)d_in[5];
    const float* com_b      = (const float*)d_in[6];
    const float* c1w        = (const float*)d_in[7];
    const float* c2w        = (const float*)d_in[8];
    float* out = (float*)d_out;

    float* ws    = (float*)d_ws;
    float* fvec  = ws;                       // 256
    float* bias2 = ws + 256;                 // 64 (pad to 512)
    float* w2    = ws + 512;                 // 147456
    float* ys    = w2 + 147456;              // 589824
    float* xs    = ys + 589824;              // 589824
    float* mk    = xs + 589824;              // 589824

    prep_kernel<<<1, 256, 0, stream>>>(c1w, fea, c2w, bias, fvec, bias2);
    w2_kernel<<<576, 256, 0, stream>>>(weight, c2w, fvec, w2);
    conv_off_kernel<<<dim3(8,8,4), 256, 0, stream>>>(inter, com_w, com_b, ys, xs, mk);
    dcn_main_kernel<<<dim3(8,8,4), 256, 0, stream>>>(input_feat, w2, bias2, ys, xs, mk, out);
}

// Round 2
// 391.909 us; speedup vs baseline: 1.2073x; 1.2073x over previous
//
#include <hip/hip_runtime.h>
#include <math.h>

// Problem constants
#define BB 4
#define CIN 64
#define COUT 64
#define HH 128
#define WW 128
#define HW (HH*WW)

// ---------------------------------------------------------------------------
// K1: fvec[b][c] = sum_i c1_w[c][i] * fea[b][i];  bias2[o2] = sum_o c2w[o2][o]*bias[o]
// ---------------------------------------------------------------------------
__global__ void prep_kernel(const float* __restrict__ c1w,
                            const float* __restrict__ fea,
                            const float* __restrict__ c2w,
                            const float* __restrict__ bias,
                            float* __restrict__ fvec,
                            float* __restrict__ bias2) {
    int t = threadIdx.x;            // 0..255
    int b = t >> 6, c = t & 63;
    float s = 0.f;
    for (int i = 0; i < 4*CIN; ++i) s += c1w[c*(4*CIN) + i] * fea[b*(4*CIN) + i];
    fvec[t] = s;
    if (t < COUT) {
        float s2 = 0.f;
        for (int o = 0; o < COUT; ++o) s2 += c2w[t*COUT + o] * bias[o];
        bias2[t] = s2;
    }
}

// ---------------------------------------------------------------------------
// K2: W2[b][p][c][o2] = fvec[b][c] * sum_o c2_w[o2][o] * weight[o][c][p]
//     576 blocks; block = (bp, c_base of 4).  c2w transposed in LDS (+1 pad),
//     weight column staged in LDS -> inner loop is 2 LDS reads + FMA.
// ---------------------------------------------------------------------------
__global__ __launch_bounds__(256) void w2_kernel(const float* __restrict__ weight,
                          const float* __restrict__ c2w,
                          const float* __restrict__ fvec,
                          float* __restrict__ w2) {
    __shared__ float c2s[64*65];     // c2s[o][o2], padded
    __shared__ float wcol[4*64];     // wcol[ci][o]
    int tid = threadIdx.x;
    int o2 = tid & 63;
    int ci = tid >> 6;               // 0..3
    int bp = blockIdx.x >> 4;        // b*9+p
    int c_base = (blockIdx.x & 15) * 4;
    int p = bp % 9;
    int b = bp / 9;
    int c = c_base + ci;

    for (int idx = tid; idx < 4096; idx += 256) {
        int o2r = idx >> 6, oc = idx & 63;
        c2s[oc*65 + o2r] = c2w[idx];
    }
    {
        int o = tid & 63, cw = tid >> 6;
        wcol[cw*64 + o] = weight[(o*CIN + (c_base + cw))*9 + p];
    }
    __syncthreads();

    float s = 0.f;
    #pragma unroll 8
    for (int o = 0; o < COUT; ++o)
        s += c2s[o*65 + o2] * wcol[ci*64 + o];
    w2[blockIdx.x*256 + tid] = s * fvec[b*CIN + c];
}

// ---------------------------------------------------------------------------
// K3: offset conv -> raw om[b][27][HW].  Output-channel split: grid.z = b*3+g,
//     each block computes 9 channels (padded to 12) for a 16x16 pixel tile
//     from all 64 input channels.  768 blocks.
// ---------------------------------------------------------------------------
__global__ __launch_bounds__(256, 4) void conv_off_kernel(
        const float* __restrict__ inter,
        const float* __restrict__ com_w,
        float* __restrict__ om) {
    __shared__ float wls[16*9*12];   // [cl*9+k][oc padded to 12]
    int bz = blockIdx.z;
    int b = bz / 3, g = bz % 3;
    int oc0 = g * 9;
    int x = blockIdx.x*16 + (threadIdx.x & 15);
    int y = blockIdx.y*16 + (threadIdx.x >> 4);

    float acc[12];
    #pragma unroll
    for (int i = 0; i < 12; ++i) acc[i] = 0.f;

    for (int cc = 0; cc < CIN; cc += 16) {
        __syncthreads();
        for (int i = threadIdx.x; i < 16*9*12; i += 256) {
            int oc = i % 12; int ck = i / 12;
            int cl = ck / 9; int k = ck % 9;
            wls[i] = (oc < 9) ? com_w[(oc0+oc)*(CIN*9) + (cc+cl)*9 + k] : 0.f;
        }
        __syncthreads();

        const float* I = inter + (b*CIN + cc)*HW;
        for (int cl = 0; cl < 16; ++cl) {
            #pragma unroll
            for (int ky = 0; ky < 3; ++ky) {
                int yy = y + ky - 1;
                bool vy = (yy >= 0) && (yy < HH);
                #pragma unroll
                for (int kx = 0; kx < 3; ++kx) {
                    int xx = x + kx - 1;
                    float v = (vy && xx >= 0 && xx < WW) ? I[yy*WW + xx] : 0.f;
                    const float4* wrow = (const float4*)(wls + (cl*9 + ky*3 + kx)*12);
                    #pragma unroll
                    for (int og = 0; og < 3; ++og) {
                        float4 wv = wrow[og];
                        acc[og*4+0] += wv.x * v;
                        acc[og*4+1] += wv.y * v;
                        acc[og*4+2] += wv.z * v;
                        acc[og*4+3] += wv.w * v;
                    }
                }
            }
            I += HW;
        }
    }

    int pix = y*WW + x;
    #pragma unroll
    for (int j = 0; j < 9; ++j)
        om[((size_t)b*27 + oc0 + j)*HW + pix] = acc[j];
}

// ---------------------------------------------------------------------------
// K4: main DCN GEMM with LDS-staged val.
//     Block = 256 thr = 64 pixels (16x4 tile) x 4 groups. Grid (8,32,4)=1024.
//     Stage phase: group g computes val for c in [16g,16g+16) -> vls[c][pix].
//     GEMM phase: group g owns outputs [16g,16g+16): acc[16] per thread.
//     Coord/sigmoid math from raw om folded in here (no ys/xs/mk buffers).
// ---------------------------------------------------------------------------
__global__ __launch_bounds__(256, 4) void dcn_main_kernel(
        const float* __restrict__ input_feat,
        const float* __restrict__ w2,
        const float* __restrict__ bias2,
        const float* __restrict__ om,
        const float* __restrict__ com_b,
        float* __restrict__ out) {
    __shared__ float w2s[64*64];     // [c][o2] for current p
    __shared__ float vls[64*64];     // [c][pix]
    int b = blockIdx.z;
    int pixl = threadIdx.x & 63;
    int grp  = threadIdx.x >> 6;     // c-group in stage, o-group in GEMM
    int xl = pixl & 15, yl = pixl >> 4;
    int x = blockIdx.x*16 + xl;
    int y = blockIdx.y*4  + yl;
    int pix = y*WW + x;
    const float* F = input_feat + (size_t)b*CIN*HW;
    const float* omb = om + (size_t)b*27*HW;

    float acc[16];
    #pragma unroll
    for (int j = 0; j < 16; ++j) acc[j] = bias2[grp*16 + j];

    for (int p = 0; p < 9; ++p) {
        __syncthreads();
        // stage w2 slice [64c][64o] = 16 KB
        {
            const float4* src = (const float4*)(w2 + (size_t)((b*9 + p)*64)*64);
            float4* dst = (float4*)w2s;
            #pragma unroll
            for (int i = 0; i < 4; ++i) dst[threadIdx.x + i*256] = src[threadIdx.x + i*256];
        }
        // coords for this pixel (replicated across the 4 groups - cheap)
        float dy = omb[(size_t)(2*p  )*HW + pix] + com_b[2*p];
        float dx = omb[(size_t)(2*p+1)*HW + pix] + com_b[2*p+1];
        float ml = omb[(size_t)(18+p )*HW + pix] + com_b[18+p];
        float mv = 1.f / (1.f + expf(-ml));
        float ysv = (float)(y - 1 + p/3) + dy;
        float xsv = (float)(x - 1 + p%3) + dx;
        float y0f = floorf(ysv), x0f = floorf(xsv);
        float ly = ysv - y0f, lx = xsv - x0f;
        int y0 = (int)y0f, x0 = (int)x0f;
        int y1 = y0 + 1, x1 = x0 + 1;
        float vy0 = (y0 >= 0 && y0 < HH) ? 1.f : 0.f;
        float vy1 = (y1 >= 0 && y1 < HH) ? 1.f : 0.f;
        float vx0 = (x0 >= 0 && x0 < WW) ? 1.f : 0.f;
        float vx1 = (x1 >= 0 && x1 < WW) ? 1.f : 0.f;
        float w00 = (1.f-ly)*(1.f-lx)*mv * vy0*vx0;
        float w01 = (1.f-ly)*lx      *mv * vy0*vx1;
        float w10 = ly      *(1.f-lx)*mv * vy1*vx0;
        float w11 = ly      *lx      *mv * vy1*vx1;
        int y0c = min(max(y0,0),HH-1), y1c = min(max(y1,0),HH-1);
        int x0c = min(max(x0,0),WW-1), x1c = min(max(x1,0),WW-1);
        int i00 = y0c*WW + x0c, i01 = y0c*WW + x1c;
        int i10 = y1c*WW + x0c, i11 = y1c*WW + x1c;

        // stage val for my 16 channels
        #pragma unroll 4
        for (int c0 = 0; c0 < 16; ++c0) {
            int c = grp*16 + c0;
            const float* Fc = F + (size_t)c*HW;
            float v = w00*Fc[i00] + w01*Fc[i01] + w10*Fc[i10] + w11*Fc[i11];
            vls[c*64 + pixl] = v;
        }
        __syncthreads();

        // GEMM phase: 16 outputs per thread over 64 channels
        #pragma unroll 4
        for (int c = 0; c < 64; ++c) {
            float v = vls[c*64 + pixl];
            const float4* wrow = (const float4*)(w2s + c*64 + grp*16);
            #pragma unroll
            for (int og = 0; og < 4; ++og) {
                float4 wv = wrow[og];
                acc[og*4+0] += wv.x * v;
                acc[og*4+1] += wv.y * v;
                acc[og*4+2] += wv.z * v;
                acc[og*4+3] += wv.w * v;
            }
        }
    }

    float* outp = out + (size_t)b*COUT*HW + pix;
    #pragma unroll
    for (int j = 0; j < 16; ++j) outp[(size_t)(grp*16 + j)*HW] = acc[j];
}

// ---------------------------------------------------------------------------
extern "C" void kernel_launch(void* const* d_in, const int* in_sizes, int n_in,
                              void* d_out, int out_size, void* d_ws, size_t ws_size,
                              hipStream_t stream) {
    const float* input_feat = (const float*)d_in[0];
    const float* inter      = (const float*)d_in[1];
    const float* fea        = (const float*)d_in[2];
    const float* weight     = (const float*)d_in[3];
    const float* bias       = (const float*)d_in[4];
    const float* com_w      = (const float*)d_in[5];
    const float* com_b      = (const float*)d_in[6];
    const float* c1w        = (const float*)d_in[7];
    const float* c2w        = (const float*)d_in[8];
    float* out = (float*)d_out;

    float* ws    = (float*)d_ws;
    float* fvec  = ws;                       // 256
    float* bias2 = ws + 256;                 // 64 (pad to 512)
    float* w2    = ws + 512;                 // 147456
    float* om    = w2 + 147456;              // 4*27*16384 = 1769472

    prep_kernel<<<1, 256, 0, stream>>>(c1w, fea, c2w, bias, fvec, bias2);
    w2_kernel<<<576, 256, 0, stream>>>(weight, c2w, fvec, w2);
    conv_off_kernel<<<dim3(8,8,12), 256, 0, stream>>>(inter, com_w, om);
    dcn_main_kernel<<<dim3(8,32,4), 256, 0, stream>>>(input_feat, w2, bias2, om, com_b, out);
}

// Round 3
// 315.809 us; speedup vs baseline: 1.4982x; 1.2410x over previous
//
#include <hip/hip_runtime.h>
#include <math.h>

// Problem constants
#define BB 4
#define CIN 64
#define COUT 64
#define HH 128
#define WW 128
#define HW (HH*WW)

// ---------------------------------------------------------------------------
// K0: zero om (ws is poisoned 0xAA before every call; conv_off atomically adds)
// ---------------------------------------------------------------------------
__global__ void zero_kernel(float4* __restrict__ p) {
    p[blockIdx.x*256 + threadIdx.x] = float4{0.f,0.f,0.f,0.f};
}

// ---------------------------------------------------------------------------
// K1: fvec[b][c] = sum_i c1_w[c][i] * fea[b][i];  bias2[o2] = sum_o c2w[o2][o]*bias[o]
// ---------------------------------------------------------------------------
__global__ void prep_kernel(const float* __restrict__ c1w,
                            const float* __restrict__ fea,
                            const float* __restrict__ c2w,
                            const float* __restrict__ bias,
                            float* __restrict__ fvec,
                            float* __restrict__ bias2) {
    int t = threadIdx.x;            // 0..255
    int b = t >> 6, c = t & 63;
    float s = 0.f;
    for (int i = 0; i < 4*CIN; ++i) s += c1w[c*(4*CIN) + i] * fea[b*(4*CIN) + i];
    fvec[t] = s;
    if (t < COUT) {
        float s2 = 0.f;
        for (int o = 0; o < COUT; ++o) s2 += c2w[t*COUT + o] * bias[o];
        bias2[t] = s2;
    }
}

// ---------------------------------------------------------------------------
// K2: W2[b][p][c][o2] = fvec[b][c] * sum_o c2_w[o2][o] * weight[o][c][p]
// ---------------------------------------------------------------------------
__global__ __launch_bounds__(256) void w2_kernel(const float* __restrict__ weight,
                          const float* __restrict__ c2w,
                          const float* __restrict__ fvec,
                          float* __restrict__ w2) {
    __shared__ float c2s[64*65];     // c2s[o][o2], padded
    __shared__ float wcol[4*64];     // wcol[ci][o]
    int tid = threadIdx.x;
    int o2 = tid & 63;
    int ci = tid >> 6;               // 0..3
    int bp = blockIdx.x >> 4;        // b*9+p
    int c_base = (blockIdx.x & 15) * 4;
    int p = bp % 9;
    int b = bp / 9;
    int c = c_base + ci;

    for (int idx = tid; idx < 4096; idx += 256) {
        int o2r = idx >> 6, oc = idx & 63;
        c2s[oc*65 + o2r] = c2w[idx];
    }
    {
        int o = tid & 63, cw = tid >> 6;
        wcol[cw*64 + o] = weight[(o*CIN + (c_base + cw))*9 + p];
    }
    __syncthreads();

    float s = 0.f;
    #pragma unroll 8
    for (int o = 0; o < COUT; ++o)
        s += c2s[o*65 + o2] * wcol[ci*64 + o];
    w2[blockIdx.x*256 + tid] = s * fvec[b*CIN + c];
}

// ---------------------------------------------------------------------------
// K3: offset conv with LDS-staged input halo tile.
//     grid (8,8,16): z = b*4 + cg;  cg = input-channel group of 16.
//     Each block: 16x16 pixel tile, 27 output channels, 16 input channels,
//     partial sums combined via fp32 atomicAdd into om[b][27][HW].
//     LDS: tile 16x(18x18)=20.7 KB + weights 16x9x28=16.1 KB -> 4 blocks/CU.
// ---------------------------------------------------------------------------
__global__ __launch_bounds__(256, 4) void conv_off_kernel(
        const float* __restrict__ inter,
        const float* __restrict__ com_w,
        float* __restrict__ om) {
    __shared__ float tile[16*324];   // [cl][18*18]
    __shared__ float wt[16*9*28];    // [cl*9+k][oc pad 28]
    int b  = blockIdx.z >> 2;
    int cg = blockIdx.z & 3;
    int x0 = blockIdx.x*16, y0 = blockIdx.y*16;
    int xl = threadIdx.x & 15, yl = threadIdx.x >> 4;

    // stage input tiles (zero-pad OOB), coalesced along rows of 18
    const float* I = inter + ((size_t)(b*CIN + cg*16))*HW;
    for (int i = threadIdx.x; i < 16*324; i += 256) {
        int ch = i / 324, rr = (i % 324) / 18, cx = i % 18;
        int gy = y0 + rr - 1, gx = x0 + cx - 1;
        float v = 0.f;
        if (gy >= 0 && gy < HH && gx >= 0 && gx < WW)
            v = I[(size_t)ch*HW + gy*WW + gx];
        tile[i] = v;
    }
    // stage weights: contiguous global reads (oc-major), strided LDS write
    for (int i = threadIdx.x; i < 27*144; i += 256) {
        int oc = i / 144, rem = i % 144;        // rem = cl*9+k
        wt[rem*28 + oc] = com_w[(size_t)oc*(CIN*9) + cg*144 + rem];
    }
    for (int i = threadIdx.x; i < 144; i += 256) wt[i*28 + 27] = 0.f;
    __syncthreads();

    float acc[28];
    #pragma unroll
    for (int i = 0; i < 28; ++i) acc[i] = 0.f;

    for (int cl = 0; cl < 16; ++cl) {
        float in9[9];
        const float* tp = tile + cl*324 + yl*18 + xl;
        #pragma unroll
        for (int ky = 0; ky < 3; ++ky)
            #pragma unroll
            for (int kx = 0; kx < 3; ++kx)
                in9[ky*3+kx] = tp[ky*18 + kx];
        #pragma unroll
        for (int k = 0; k < 9; ++k) {
            const float4* wr = (const float4*)(wt + (cl*9 + k)*28);
            float v = in9[k];
            #pragma unroll
            for (int og = 0; og < 7; ++og) {
                float4 w = wr[og];
                acc[og*4+0] += w.x * v;
                acc[og*4+1] += w.y * v;
                acc[og*4+2] += w.z * v;
                acc[og*4+3] += w.w * v;
            }
        }
    }

    int pix = (y0+yl)*WW + (x0+xl);
    float* op = om + (size_t)b*27*HW + pix;
    #pragma unroll
    for (int j = 0; j < 27; ++j)
        atomicAdd(op + (size_t)j*HW, acc[j]);
}

// ---------------------------------------------------------------------------
// K4: main DCN GEMM with LDS-staged val + software-pipelined w2/om prefetch.
//     Block = 256 thr = 64 pixels (16x4) x 4 groups. Grid (8,32,4)=1024.
// ---------------------------------------------------------------------------
__global__ __launch_bounds__(256, 4) void dcn_main_kernel(
        const float* __restrict__ input_feat,
        const float* __restrict__ w2,
        const float* __restrict__ bias2,
        const float* __restrict__ om,
        const float* __restrict__ com_b,
        float* __restrict__ out) {
    __shared__ float w2s[64*64];     // [c][o2] for current p
    __shared__ float vls[64*64];     // [c][pix]
    int b = blockIdx.z;
    int pixl = threadIdx.x & 63;
    int grp  = threadIdx.x >> 6;     // c-group in stage, o-group in GEMM
    int xl = pixl & 15, yl = pixl >> 4;
    int x = blockIdx.x*16 + xl;
    int y = blockIdx.y*4  + yl;
    int pix = y*WW + x;
    const float* F = input_feat + (size_t)b*CIN*HW;
    const float* omb = om + (size_t)b*27*HW;
    const float4* w2src = (const float4*)(w2 + (size_t)(b*9)*4096);

    // prefetch p=0 state
    float4 w2r[4];
    #pragma unroll
    for (int i = 0; i < 4; ++i) w2r[i] = w2src[threadIdx.x + i*256];
    float omy = omb[pix];
    float omx = omb[(size_t)HW + pix];
    float omm = omb[(size_t)18*HW + pix];

    float acc[16];
    #pragma unroll
    for (int j = 0; j < 16; ++j) acc[j] = bias2[grp*16 + j];

    for (int p = 0; p < 9; ++p) {
        __syncthreads();
        // write prefetched w2 slice to LDS
        {
            float4* dst = (float4*)w2s;
            #pragma unroll
            for (int i = 0; i < 4; ++i) dst[threadIdx.x + i*256] = w2r[i];
        }
        // coords for this pixel from prefetched om
        float dy = omy + com_b[2*p];
        float dx = omx + com_b[2*p+1];
        float ml = omm + com_b[18+p];
        float mv = 1.f / (1.f + expf(-ml));
        float ysv = (float)(y - 1 + p/3) + dy;
        float xsv = (float)(x - 1 + p%3) + dx;
        float y0f = floorf(ysv), x0f = floorf(xsv);
        float ly = ysv - y0f, lx = xsv - x0f;
        int y0 = (int)y0f, x0 = (int)x0f;
        int y1 = y0 + 1, x1 = x0 + 1;
        float vy0 = (y0 >= 0 && y0 < HH) ? 1.f : 0.f;
        float vy1 = (y1 >= 0 && y1 < HH) ? 1.f : 0.f;
        float vx0 = (x0 >= 0 && x0 < WW) ? 1.f : 0.f;
        float vx1 = (x1 >= 0 && x1 < WW) ? 1.f : 0.f;
        float w00 = (1.f-ly)*(1.f-lx)*mv * vy0*vx0;
        float w01 = (1.f-ly)*lx      *mv * vy0*vx1;
        float w10 = ly      *(1.f-lx)*mv * vy1*vx0;
        float w11 = ly      *lx      *mv * vy1*vx1;
        int y0c = min(max(y0,0),HH-1), y1c = min(max(y1,0),HH-1);
        int x0c = min(max(x0,0),WW-1), x1c = min(max(x1,0),WW-1);
        int i00 = y0c*WW + x0c, i01 = y0c*WW + x1c;
        int i10 = y1c*WW + x0c, i11 = y1c*WW + x1c;

        // stage val for my 16 channels
        #pragma unroll 4
        for (int c0 = 0; c0 < 16; ++c0) {
            int c = grp*16 + c0;
            const float* Fc = F + (size_t)c*HW;
            float v = w00*Fc[i00] + w01*Fc[i01] + w10*Fc[i10] + w11*Fc[i11];
            vls[c*64 + pixl] = v;
        }
        __syncthreads();

        // prefetch next p's w2 + om while GEMM runs
        if (p < 8) {
            #pragma unroll
            for (int i = 0; i < 4; ++i)
                w2r[i] = w2src[(p+1)*1024 + threadIdx.x + i*256];
            omy = omb[(size_t)(2*p+2)*HW + pix];
            omx = omb[(size_t)(2*p+3)*HW + pix];
            omm = omb[(size_t)(19+p )*HW + pix];
        }

        // GEMM phase: 16 outputs per thread over 64 channels
        #pragma unroll 4
        for (int c = 0; c < 64; ++c) {
            float v = vls[c*64 + pixl];
            const float4* wrow = (const float4*)(w2s + c*64 + grp*16);
            #pragma unroll
            for (int og = 0; og < 4; ++og) {
                float4 wv = wrow[og];
                acc[og*4+0] += wv.x * v;
                acc[og*4+1] += wv.y * v;
                acc[og*4+2] += wv.z * v;
                acc[og*4+3] += wv.w * v;
            }
        }
    }

    float* outp = out + (size_t)b*COUT*HW + pix;
    #pragma unroll
    for (int j = 0; j < 16; ++j) outp[(size_t)(grp*16 + j)*HW] = acc[j];
}

// ---------------------------------------------------------------------------
extern "C" void kernel_launch(void* const* d_in, const int* in_sizes, int n_in,
                              void* d_out, int out_size, void* d_ws, size_t ws_size,
                              hipStream_t stream) {
    const float* input_feat = (const float*)d_in[0];
    const float* inter      = (const float*)d_in[1];
    const float* fea        = (const float*)d_in[2];
    const float* weight     = (const float*)d_in[3];
    const float* bias       = (const float*)d_in[4];
    const float* com_w      = (const float*)d_in[5];
    const float* com_b      = (const float*)d_in[6];
    const float* c1w        = (const float*)d_in[7];
    const float* c2w        = (const float*)d_in[8];
    float* out = (float*)d_out;

    float* ws    = (float*)d_ws;
    float* fvec  = ws;                       // 256
    float* bias2 = ws + 256;                 // 64 (pad to 512)
    float* w2    = ws + 512;                 // 147456
    float* om    = w2 + 147456;              // 4*27*16384 = 1769472

    zero_kernel<<<1728, 256, 0, stream>>>((float4*)om);   // 1769472/4/256
    prep_kernel<<<1, 256, 0, stream>>>(c1w, fea, c2w, bias, fvec, bias2);
    w2_kernel<<<576, 256, 0, stream>>>(weight, c2w, fvec, w2);
    conv_off_kernel<<<dim3(8,8,16), 256, 0, stream>>>(inter, com_w, om);
    dcn_main_kernel<<<dim3(8,32,4), 256, 0, stream>>>(input_feat, w2, bias2, om, com_b, out);
}

// Round 4
// 286.081 us; speedup vs baseline: 1.6539x; 1.1039x over previous
//
#include <hip/hip_runtime.h>
#include <math.h>

// Problem constants
#define BB 4
#define CIN 64
#define COUT 64
#define HH 128
#define WW 128
#define HW (HH*WW)

typedef __attribute__((ext_vector_type(8))) short short8;   // 8 bf16 = 4 VGPRs
typedef __attribute__((ext_vector_type(4))) float f32x4;

static __device__ __forceinline__ unsigned short f2bf(float f) {
    unsigned int u = __builtin_bit_cast(unsigned int, f);
    u += 0x7fffu + ((u >> 16) & 1u);          // round-to-nearest-even
    return (unsigned short)(u >> 16);
}

// ---------------------------------------------------------------------------
// K0: zero om (conv_off accumulates with atomicAdd; ws is poisoned 0xAA)
// ---------------------------------------------------------------------------
__global__ void zero_kernel(float4* __restrict__ p) {
    p[blockIdx.x*256 + threadIdx.x] = float4{0.f,0.f,0.f,0.f};
}

// ---------------------------------------------------------------------------
// K1: fvec[b][c] = sum_i c1_w[c][i]*fea[b][i];  bias2[o2] = sum_o c2w[o2][o]*bias[o]
// ---------------------------------------------------------------------------
__global__ void prep_kernel(const float* __restrict__ c1w,
                            const float* __restrict__ fea,
                            const float* __restrict__ c2w,
                            const float* __restrict__ bias,
                            float* __restrict__ fvec,
                            float* __restrict__ bias2) {
    int t = threadIdx.x;            // 0..255
    int b = t >> 6, c = t & 63;
    float s = 0.f;
    for (int i = 0; i < 4*CIN; ++i) s += c1w[c*(4*CIN) + i] * fea[b*(4*CIN) + i];
    fvec[t] = s;
    if (t < COUT) {
        float s2 = 0.f;
        for (int o = 0; o < COUT; ++o) s2 += c2w[t*COUT + o] * bias[o];
        bias2[t] = s2;
    }
}

// ---------------------------------------------------------------------------
// K2: W2b[b][p][o2][c] (bf16, MFMA A-operand layout: k=c contiguous per o2 row)
//     W2 = fvec[b][c] * sum_o c2_w[o2][o] * weight[o][c][p]
// ---------------------------------------------------------------------------
__global__ __launch_bounds__(256) void w2_kernel(const float* __restrict__ weight,
                          const float* __restrict__ c2w,
                          const float* __restrict__ fvec,
                          unsigned short* __restrict__ w2b) {
    __shared__ float c2s[64*65];     // c2s[o][o2], padded
    __shared__ float wcol[4*64];     // wcol[ci][o]
    int tid = threadIdx.x;
    int o2 = tid & 63;
    int ci = tid >> 6;               // 0..3
    int bp = blockIdx.x >> 4;        // b*9+p
    int c_base = (blockIdx.x & 15) * 4;
    int p = bp % 9;
    int b = bp / 9;
    int c = c_base + ci;

    for (int idx = tid; idx < 4096; idx += 256) {
        int o2r = idx >> 6, oc = idx & 63;
        c2s[oc*65 + o2r] = c2w[idx];
    }
    {
        int o = tid & 63, cw = tid >> 6;
        wcol[cw*64 + o] = weight[(o*CIN + (c_base + cw))*9 + p];
    }
    __syncthreads();

    float s = 0.f;
    #pragma unroll 8
    for (int o = 0; o < COUT; ++o)
        s += c2s[o*65 + o2] * wcol[ci*64 + o];
    // layout: [bp][o2][c]
    w2b[(size_t)bp*4096 + o2*64 + c] = f2bf(s * fvec[b*CIN + c]);
}

// ---------------------------------------------------------------------------
// K3: offset conv.  Input halo tile in LDS; weights read wave-uniform from
//     global (scalar s_load path) - no LDS weight traffic.
//     grid (8,8,16): z = b*4+cg, cg = 16-input-channel group; atomicAdd to om.
// ---------------------------------------------------------------------------
__global__ __launch_bounds__(256) void conv_off_kernel(
        const float* __restrict__ inter,
        const float* __restrict__ com_w,
        float* __restrict__ om) {
    __shared__ float tile[16*324];   // [cl][18*18] = 20.7 KB
    int b  = blockIdx.z >> 2;
    int cg = blockIdx.z & 3;
    int x0 = blockIdx.x*16, y0 = blockIdx.y*16;
    int xl = threadIdx.x & 15, yl = threadIdx.x >> 4;

    const float* I = inter + ((size_t)(b*CIN + cg*16))*HW;
    for (int i = threadIdx.x; i < 16*324; i += 256) {
        int ch = i / 324, rr = (i % 324) / 18, cx = i % 18;
        int gy = y0 + rr - 1, gx = x0 + cx - 1;
        float v = 0.f;
        if (gy >= 0 && gy < HH && gx >= 0 && gx < WW)
            v = I[(size_t)ch*HW + gy*WW + gx];
        tile[i] = v;
    }
    __syncthreads();

    float acc[27];
    #pragma unroll
    for (int i = 0; i < 27; ++i) acc[i] = 0.f;

    for (int cl = 0; cl < 16; ++cl) {
        float in9[9];
        const float* tp = tile + cl*324 + yl*18 + xl;
        #pragma unroll
        for (int ky = 0; ky < 3; ++ky)
            #pragma unroll
            for (int kx = 0; kx < 3; ++kx)
                in9[ky*3+kx] = tp[ky*18 + kx];
        // wave-uniform weight rows (9 contiguous floats per oc) -> s_loads
        const float* wp = com_w + (size_t)cg*144 + cl*9;
        #pragma unroll
        for (int oc = 0; oc < 27; ++oc) {
            const float* w9 = wp + (size_t)oc*576;
            float a = acc[oc];
            #pragma unroll
            for (int k = 0; k < 9; ++k) a += w9[k] * in9[k];
            acc[oc] = a;
        }
    }

    int pix = (y0+yl)*WW + (x0+xl);
    float* op = om + (size_t)b*27*HW + pix;
    #pragma unroll
    for (int j = 0; j < 27; ++j)
        atomicAdd(op + (size_t)j*HW, acc[j]);
}

// ---------------------------------------------------------------------------
// K4: main DCN GEMM via bf16 MFMA.
//     Block = 256 thr = 4 waves; 64 pixels (16x4 tile). Grid (8,32,4)=1024.
//     Gather phase: thread (pixl=t&63, grp=t>>6) computes val for 16 channels,
//     writes bf16 to vls[pixl][c] (row stride 72).
//     MFMA phase: wave w owns n-tile = pixel row w (16 px), computes all 64 o2
//     as 4 m-tiles x 2 K-steps of mfma_f32_16x16x32_bf16 per p.
//     A-frags direct from global (w2b, L2-hot), B-frags ds_read_b128 from vls.
// ---------------------------------------------------------------------------
__global__ __launch_bounds__(256) void dcn_main_kernel(
        const float* __restrict__ input_feat,
        const unsigned short* __restrict__ w2b,
        const float* __restrict__ bias2,
        const float* __restrict__ om,
        const float* __restrict__ com_b,
        float* __restrict__ out) {
    __shared__ __align__(16) unsigned short vls[64*72];   // 9216 B
    int b = blockIdx.z;
    int t = threadIdx.x;
    int pixl = t & 63;
    int grp  = t >> 6;
    int xl = pixl & 15, yl = pixl >> 4;
    int x = blockIdx.x*16 + xl;
    int y = blockIdx.y*4  + yl;
    int pix = y*WW + x;
    const float* F = input_feat + (size_t)b*CIN*HW;
    const float* omb = om + (size_t)b*27*HW;

    // MFMA lane ids
    int lane = t & 63, wv = t >> 6;
    int nn = lane & 15, qq = lane >> 4;

    f32x4 acc[4];
    #pragma unroll
    for (int mt = 0; mt < 4; ++mt)
        #pragma unroll
        for (int j = 0; j < 4; ++j)
            acc[mt][j] = bias2[mt*16 + qq*4 + j];

    // prefetch p=0 om
    float omy = omb[pix];
    float omx = omb[(size_t)HW + pix];
    float omm = omb[(size_t)18*HW + pix];

    for (int p = 0; p < 9; ++p) {
        // ---- A-frag prefetch for this p (global, overlaps everything) ----
        short8 afr[4][2];
        {
            size_t base = ((size_t)(b*9 + p)*64)*64;
            #pragma unroll
            for (int mt = 0; mt < 4; ++mt)
                #pragma unroll
                for (int ks = 0; ks < 2; ++ks)
                    afr[mt][ks] = *(const short8*)(w2b + base
                                    + (size_t)(mt*16 + nn)*64 + ks*32 + qq*8);
        }

        // ---- bilinear corner weights for my pixel ----
        float dy = omy + com_b[2*p];
        float dx = omx + com_b[2*p+1];
        float ml = omm + com_b[18+p];
        float mv = 1.f / (1.f + expf(-ml));
        float ysv = (float)(y - 1 + p/3) + dy;
        float xsv = (float)(x - 1 + p%3) + dx;
        float y0f = floorf(ysv), x0f = floorf(xsv);
        float ly = ysv - y0f, lx = xsv - x0f;
        int y0 = (int)y0f, x0 = (int)x0f;
        int y1 = y0 + 1, x1 = x0 + 1;
        float vy0 = (y0 >= 0 && y0 < HH) ? 1.f : 0.f;
        float vy1 = (y1 >= 0 && y1 < HH) ? 1.f : 0.f;
        float vx0 = (x0 >= 0 && x0 < WW) ? 1.f : 0.f;
        float vx1 = (x1 >= 0 && x1 < WW) ? 1.f : 0.f;
        float w00 = (1.f-ly)*(1.f-lx)*mv * vy0*vx0;
        float w01 = (1.f-ly)*lx      *mv * vy0*vx1;
        float w10 = ly      *(1.f-lx)*mv * vy1*vx0;
        float w11 = ly      *lx      *mv * vy1*vx1;
        int y0c = min(max(y0,0),HH-1), y1c = min(max(y1,0),HH-1);
        int x0c = min(max(x0,0),WW-1), x1c = min(max(x1,0),WW-1);
        int i00 = y0c*WW + x0c, i01 = y0c*WW + x1c;
        int i10 = y1c*WW + x0c, i11 = y1c*WW + x1c;

        // ---- gather 16 channels -> bf16 packs ----
        ushort4 vb4[4];
        #pragma unroll
        for (int c4 = 0; c4 < 4; ++c4) {
            unsigned short bs[4];
            #pragma unroll
            for (int ci = 0; ci < 4; ++ci) {
                int c = grp*16 + c4*4 + ci;
                const float* Fc = F + (size_t)c*HW;
                float v = w00*Fc[i00] + w01*Fc[i01] + w10*Fc[i10] + w11*Fc[i11];
                bs[ci] = f2bf(v);
            }
            vb4[c4] = ushort4{bs[0], bs[1], bs[2], bs[3]};
        }

        // ---- prefetch next p's om ----
        if (p < 8) {
            omy = omb[(size_t)(2*p+2)*HW + pix];
            omx = omb[(size_t)(2*p+3)*HW + pix];
            omm = omb[(size_t)(19+p )*HW + pix];
        }

        __syncthreads();   // previous MFMA reads of vls complete
        {
            ushort4* dst = (ushort4*)(vls + pixl*72 + grp*16);
            #pragma unroll
            for (int c4 = 0; c4 < 4; ++c4) dst[c4] = vb4[c4];
        }
        __syncthreads();   // vls ready

        // ---- MFMA phase: wave wv's 16 pixels, all 64 outputs ----
        #pragma unroll
        for (int ks = 0; ks < 2; ++ks) {
            short8 bfr = *(const short8*)(vls + (wv*16 + nn)*72 + ks*32 + qq*8);
            #pragma unroll
            for (int mt = 0; mt < 4; ++mt)
                acc[mt] = __builtin_amdgcn_mfma_f32_16x16x32_bf16(
                              afr[mt][ks], bfr, acc[mt], 0, 0, 0);
        }
    }

    // ---- epilogue: D[m=qq*4+j][n=nn] ----
    float* outp = out + (size_t)b*COUT*HW
                + (size_t)(blockIdx.y*4 + wv)*WW + blockIdx.x*16 + nn;
    #pragma unroll
    for (int mt = 0; mt < 4; ++mt)
        #pragma unroll
        for (int j = 0; j < 4; ++j)
            outp[(size_t)(mt*16 + qq*4 + j)*HW] = acc[mt][j];
}

// ---------------------------------------------------------------------------
extern "C" void kernel_launch(void* const* d_in, const int* in_sizes, int n_in,
                              void* d_out, int out_size, void* d_ws, size_t ws_size,
                              hipStream_t stream) {
    const float* input_feat = (const float*)d_in[0];
    const float* inter      = (const float*)d_in[1];
    const float* fea        = (const float*)d_in[2];
    const float* weight     = (const float*)d_in[3];
    const float* bias       = (const float*)d_in[4];
    const float* com_w      = (const float*)d_in[5];
    const float* com_b      = (const float*)d_in[6];
    const float* c1w        = (const float*)d_in[7];
    const float* c2w        = (const float*)d_in[8];
    float* out = (float*)d_out;

    float* ws    = (float*)d_ws;
    float* fvec  = ws;                            // 256 floats
    float* bias2 = ws + 256;                      // 64 (pad to 512)
    unsigned short* w2b = (unsigned short*)(ws + 512);   // 147456 ushort = 73728 floats
    float* om    = ws + 512 + 73728;              // 4*27*16384 = 1769472 floats

    zero_kernel<<<1728, 256, 0, stream>>>((float4*)om);
    prep_kernel<<<1, 256, 0, stream>>>(c1w, fea, c2w, bias, fvec, bias2);
    w2_kernel<<<576, 256, 0, stream>>>(weight, c2w, fvec, w2b);
    conv_off_kernel<<<dim3(8,8,16), 256, 0, stream>>>(inter, com_w, om);
    dcn_main_kernel<<<dim3(8,32,4), 256, 0, stream>>>(input_feat, w2b, bias2, om, com_b, out);
}

// Round 6
// 250.441 us; speedup vs baseline: 1.8893x; 1.1423x over previous
//
#include <hip/hip_runtime.h>
#include <math.h>

// Problem constants
#define BB 4
#define CIN 64
#define COUT 64
#define HH 128
#define WW 128
#define HW (HH*WW)

typedef __attribute__((ext_vector_type(8))) short short8;   // 8 bf16 = 4 VGPRs
typedef __attribute__((ext_vector_type(4))) float f32x4;

static __device__ __forceinline__ unsigned short f2bf(float f) {
    unsigned int u = __builtin_bit_cast(unsigned int, f);
    u += 0x7fffu + ((u >> 16) & 1u);          // round-to-nearest-even
    return (unsigned short)(u >> 16);
}

// ---------------------------------------------------------------------------
// K0: zero om (conv_off accumulates with atomicAdd; ws is poisoned 0xAA)
// ---------------------------------------------------------------------------
__global__ void zero_kernel(float4* __restrict__ p) {
    p[blockIdx.x*256 + threadIdx.x] = float4{0.f,0.f,0.f,0.f};
}

// ---------------------------------------------------------------------------
// K1: fvec[b][c] = sum_i c1_w[c][i]*fea[b][i];  bias2[o2] = sum_o c2w[o2][o]*bias[o]
// ---------------------------------------------------------------------------
__global__ void prep_kernel(const float* __restrict__ c1w,
                            const float* __restrict__ fea,
                            const float* __restrict__ c2w,
                            const float* __restrict__ bias,
                            float* __restrict__ fvec,
                            float* __restrict__ bias2) {
    int t = threadIdx.x;            // 0..255
    int b = t >> 6, c = t & 63;
    float s = 0.f;
    for (int i = 0; i < 4*CIN; ++i) s += c1w[c*(4*CIN) + i] * fea[b*(4*CIN) + i];
    fvec[t] = s;
    if (t < COUT) {
        float s2 = 0.f;
        for (int o = 0; o < COUT; ++o) s2 += c2w[t*COUT + o] * bias[o];
        bias2[t] = s2;
    }
}

// ---------------------------------------------------------------------------
// K2: W2b[b][p][o2][c] (bf16, MFMA A-operand layout: k=c contiguous per o2 row)
// ---------------------------------------------------------------------------
__global__ __launch_bounds__(256) void w2_kernel(const float* __restrict__ weight,
                          const float* __restrict__ c2w,
                          const float* __restrict__ fvec,
                          unsigned short* __restrict__ w2b) {
    __shared__ float c2s[64*65];     // c2s[o][o2], padded
    __shared__ float wcol[4*64];     // wcol[ci][o]
    int tid = threadIdx.x;
    int o2 = tid & 63;
    int ci = tid >> 6;               // 0..3
    int bp = blockIdx.x >> 4;        // b*9+p
    int c_base = (blockIdx.x & 15) * 4;
    int p = bp % 9;
    int b = bp / 9;
    int c = c_base + ci;

    for (int idx = tid; idx < 4096; idx += 256) {
        int o2r = idx >> 6, oc = idx & 63;
        c2s[oc*65 + o2r] = c2w[idx];
    }
    {
        int o = tid & 63, cw = tid >> 6;
        wcol[cw*64 + o] = weight[(o*CIN + (c_base + cw))*9 + p];
    }
    __syncthreads();

    float s = 0.f;
    #pragma unroll 8
    for (int o = 0; o < COUT; ++o)
        s += c2s[o*65 + o2] * wcol[ci*64 + o];
    w2b[(size_t)bp*4096 + o2*64 + c] = f2bf(s * fvec[b*CIN + c]);
}

// ---------------------------------------------------------------------------
// K2b: prepack com_w for MFMA conv.
//      wk2[cg][chunk][oc(32)][k(32)]: k<16 -> tap=2*chunk, k>=16 -> tap=2*chunk+1,
//      c = cg*16 + (k&15).  tap 9 / oc>=27 -> 0.
// ---------------------------------------------------------------------------
__global__ void wkpack_kernel(const float* __restrict__ com_w,
                              unsigned short* __restrict__ wk2) {
    int i = blockIdx.x*256 + threadIdx.x;   // < 20480
    int k  = i & 31;
    int oc = (i >> 5) & 31;
    int cc5 = i >> 10;                      // cg*5 + chunk
    int cg = cc5 / 5, ch = cc5 % 5;
    int tap = ch*2 + (k >> 4);
    int c = cg*16 + (k & 15);
    float v = 0.f;
    if (tap < 9 && oc < 27) v = com_w[((size_t)oc*64 + c)*9 + tap];
    wk2[i] = f2bf(v);
}

// ---------------------------------------------------------------------------
// K3: offset conv via bf16 MFMA (im2col-in-LDS).  __syncthreads-protected.
//     grid (8,8,16): z = b*4+cg.  Block: 16x16 px tile, 16 input channels.
// ---------------------------------------------------------------------------
#define TSTR 24
__global__ __launch_bounds__(256) void conv_off_kernel(
        const float* __restrict__ inter,
        const unsigned short* __restrict__ wk2,
        float* __restrict__ om) {
    __shared__ __align__(16) unsigned short til[325*TSTR];   // 15.6 KB
    int b  = blockIdx.z >> 2;
    int cg = blockIdx.z & 3;
    int x0 = blockIdx.x*16, y0 = blockIdx.y*16;
    int tid = threadIdx.x;

    const float* I = inter + ((size_t)(b*CIN + cg*16))*HW;
    for (int i = tid; i < 16*324; i += 256) {
        int cl = i / 324, px = i % 324;
        int r = px / 18, cc = px % 18;
        int gy = y0 + r - 1, gx = x0 + cc - 1;
        float v = 0.f;
        if (gy >= 0 && gy < HH && gx >= 0 && gx < WW)
            v = I[(size_t)cl*HW + gy*WW + gx];
        til[px*TSTR + cl] = f2bf(v);
    }
    if (tid < TSTR) til[324*TSTR + tid] = 0;   // zero row for tap-9 dummy
    __syncthreads();

    int lane = tid & 63, wv = tid >> 6;
    int nn = lane & 15, qq = lane >> 4;

    // A-frags (L2-hot global): afr[chunk][mt]; A[m=nn][k=qq*8+j]
    short8 afr[5][2];
    #pragma unroll
    for (int ch = 0; ch < 5; ++ch)
        #pragma unroll
        for (int mt = 0; mt < 2; ++mt)
            afr[ch][mt] = *(const short8*)(wk2 +
                (((size_t)(cg*5 + ch)*32 + mt*16 + nn)*32 + qq*8));

    f32x4 acc[4][2];
    #pragma unroll
    for (int nt = 0; nt < 4; ++nt)
        #pragma unroll
        for (int mt = 0; mt < 2; ++mt)
            #pragma unroll
            for (int j = 0; j < 4; ++j) acc[nt][mt][j] = 0.f;

    #pragma unroll
    for (int nt = 0; nt < 4; ++nt) {
        int row = wv*4 + nt;
        #pragma unroll
        for (int ch = 0; ch < 5; ++ch) {
            int tap = ch*2 + (qq >> 1);
            int px_idx;
            if (tap > 8) px_idx = 324;                       // zero row
            else {
                int ky = tap / 3, kx = tap % 3;
                px_idx = (row + ky)*18 + (nn + kx);
            }
            short8 bfr = *(const short8*)(til + px_idx*TSTR + (qq & 1)*8);
            acc[nt][0] = __builtin_amdgcn_mfma_f32_16x16x32_bf16(
                             afr[ch][0], bfr, acc[nt][0], 0, 0, 0);
            acc[nt][1] = __builtin_amdgcn_mfma_f32_16x16x32_bf16(
                             afr[ch][1], bfr, acc[nt][1], 0, 0, 0);
        }
    }

    float* op = om + (size_t)b*27*HW;
    #pragma unroll
    for (int nt = 0; nt < 4; ++nt) {
        int pix = (y0 + wv*4 + nt)*WW + x0 + nn;
        #pragma unroll
        for (int mt = 0; mt < 2; ++mt)
            #pragma unroll
            for (int j = 0; j < 4; ++j) {
                int oc = mt*16 + qq*4 + j;
                if (oc < 27)
                    atomicAdd(op + (size_t)oc*HW + pix, acc[nt][mt][j]);
            }
    }
}

// ---------------------------------------------------------------------------
// K4: main DCN GEMM via bf16 MFMA -- NO LDS, NO BARRIERS, NO CROSS-LANE.
//     Lane (nn=lane&15, qq=lane>>4) gathers exactly the 16 channels its own
//     B-fragment needs: c in {ks*32 + qq*8 + j}, packs short8 in registers.
//     Wave owns a 16-px strip; grid (2,128,4) = 1024 blocks, 4 waves each.
// ---------------------------------------------------------------------------
__global__ __launch_bounds__(256) void dcn_main_kernel(
        const float* __restrict__ input_feat,
        const unsigned short* __restrict__ w2b,
        const float* __restrict__ bias2,
        const float* __restrict__ om,
        const float* __restrict__ com_b,
        float* __restrict__ out) {
    int b = blockIdx.z;
    int t = threadIdx.x;
    int lane = t & 63, wv = t >> 6;
    int nn = lane & 15, qq = lane >> 4;
    int px0 = blockIdx.x*64 + wv*16;
    int y = blockIdx.y;
    int x = px0 + nn;
    int pix = y*WW + x;
    const float* F = input_feat + (size_t)b*CIN*HW;
    const float* omb = om + (size_t)b*27*HW;

    f32x4 acc[4];
    #pragma unroll
    for (int mt = 0; mt < 4; ++mt)
        #pragma unroll
        for (int j = 0; j < 4; ++j)
            acc[mt][j] = bias2[mt*16 + qq*4 + j];

    // prefetch p=0 om (4x redundant across qq, same px -- cheap)
    float omy = omb[pix];
    float omx = omb[(size_t)HW + pix];
    float omm = omb[(size_t)18*HW + pix];

    for (int p = 0; p < 9; ++p) {
        // A-frag loads for this p (global, L2-hot)
        short8 afr[4][2];
        {
            size_t base = ((size_t)(b*9 + p)*64)*64;
            #pragma unroll
            for (int mt = 0; mt < 4; ++mt)
                #pragma unroll
                for (int ks = 0; ks < 2; ++ks)
                    afr[mt][ks] = *(const short8*)(w2b + base
                                    + (size_t)(mt*16 + nn)*64 + ks*32 + qq*8);
        }

        // bilinear corner weights for my pixel
        float dy = omy + com_b[2*p];
        float dx = omx + com_b[2*p+1];
        float ml = omm + com_b[18+p];
        float mv = 1.f / (1.f + expf(-ml));
        float ysv = (float)(y - 1 + p/3) + dy;
        float xsv = (float)(x - 1 + p%3) + dx;
        float y0f = floorf(ysv), x0f = floorf(xsv);
        float ly = ysv - y0f, lx = xsv - x0f;
        int y0 = (int)y0f, x0i = (int)x0f;
        int y1 = y0 + 1, x1 = x0i + 1;
        float vy0 = (y0 >= 0 && y0 < HH) ? 1.f : 0.f;
        float vy1 = (y1 >= 0 && y1 < HH) ? 1.f : 0.f;
        float vx0 = (x0i >= 0 && x0i < WW) ? 1.f : 0.f;
        float vx1 = (x1 >= 0 && x1 < WW) ? 1.f : 0.f;
        float w00 = (1.f-ly)*(1.f-lx)*mv * vy0*vx0;
        float w01 = (1.f-ly)*lx      *mv * vy0*vx1;
        float w10 = ly      *(1.f-lx)*mv * vy1*vx0;
        float w11 = ly      *lx      *mv * vy1*vx1;
        int y0c = min(max(y0,0),HH-1), y1c = min(max(y1,0),HH-1);
        int x0c = min(max(x0i,0),WW-1), x1c = min(max(x1,0),WW-1);
        int i00 = y0c*WW + x0c, i01 = y0c*WW + x1c;
        int i10 = y1c*WW + x0c, i11 = y1c*WW + x1c;

        // gather MY B-frag channels directly into registers (no LDS!)
        short8 bfr[2];
        #pragma unroll
        for (int ks = 0; ks < 2; ++ks) {
            short8 pk;
            #pragma unroll
            for (int j = 0; j < 8; ++j) {
                int c = ks*32 + qq*8 + j;
                const float* Fc = F + (size_t)c*HW;
                float v = w00*Fc[i00] + w01*Fc[i01] + w10*Fc[i10] + w11*Fc[i11];
                pk[j] = (short)f2bf(v);
            }
            bfr[ks] = pk;
        }

        // prefetch next p's om
        if (p < 8) {
            omy = omb[(size_t)(2*p+2)*HW + pix];
            omx = omb[(size_t)(2*p+3)*HW + pix];
            omm = omb[(size_t)(19+p )*HW + pix];
        }

        // MFMA: B[k=ks*32+qq*8+j][n=nn], all from this lane's registers
        #pragma unroll
        for (int ks = 0; ks < 2; ++ks)
            #pragma unroll
            for (int mt = 0; mt < 4; ++mt)
                acc[mt] = __builtin_amdgcn_mfma_f32_16x16x32_bf16(
                              afr[mt][ks], bfr[ks], acc[mt], 0, 0, 0);
    }

    // epilogue: D[m=qq*4+j][n=nn]
    float* outp = out + (size_t)b*COUT*HW + (size_t)y*WW + px0 + nn;
    #pragma unroll
    for (int mt = 0; mt < 4; ++mt)
        #pragma unroll
        for (int j = 0; j < 4; ++j)
            outp[(size_t)(mt*16 + qq*4 + j)*HW] = acc[mt][j];
}

// ---------------------------------------------------------------------------
extern "C" void kernel_launch(void* const* d_in, const int* in_sizes, int n_in,
                              void* d_out, int out_size, void* d_ws, size_t ws_size,
                              hipStream_t stream) {
    const float* input_feat = (const float*)d_in[0];
    const float* inter      = (const float*)d_in[1];
    const float* fea        = (const float*)d_in[2];
    const float* weight     = (const float*)d_in[3];
    const float* bias       = (const float*)d_in[4];
    const float* com_w      = (const float*)d_in[5];
    const float* com_b      = (const float*)d_in[6];
    const float* c1w        = (const float*)d_in[7];
    const float* c2w        = (const float*)d_in[8];
    float* out = (float*)d_out;

    float* ws    = (float*)d_ws;
    float* fvec  = ws;                                   // 256 floats
    float* bias2 = ws + 256;                             // 64 (pad to 512)
    unsigned short* w2b = (unsigned short*)(ws + 512);   // 147456 ushort
    float* om    = ws + 512 + 73728;                     // 1769472 floats
    unsigned short* wk2 = (unsigned short*)(om + 1769472); // 20480 ushort

    zero_kernel<<<1728, 256, 0, stream>>>((float4*)om);
    prep_kernel<<<1, 256, 0, stream>>>(c1w, fea, c2w, bias, fvec, bias2);
    w2_kernel<<<576, 256, 0, stream>>>(weight, c2w, fvec, w2b);
    wkpack_kernel<<<80, 256, 0, stream>>>(com_w, wk2);
    conv_off_kernel<<<dim3(8,8,16), 256, 0, stream>>>(inter, wk2, om);
    dcn_main_kernel<<<dim3(2,128,4), 256, 0, stream>>>(input_feat, w2b, bias2, om, com_b, out);
}

// Round 7
// 225.734 us; speedup vs baseline: 2.0961x; 1.1095x over previous
//
#include <hip/hip_runtime.h>
#include <math.h>

// Problem constants
#define BB 4
#define CIN 64
#define COUT 64
#define HH 128
#define WW 128
#define HW (HH*WW)

typedef __attribute__((ext_vector_type(8))) short short8;   // 8 bf16 = 4 VGPRs
typedef __attribute__((ext_vector_type(4))) float f32x4;

static __device__ __forceinline__ unsigned short f2bf(float f) {
    unsigned int u = __builtin_bit_cast(unsigned int, f);
    u += 0x7fffu + ((u >> 16) & 1u);          // round-to-nearest-even
    return (unsigned short)(u >> 16);
}
static __device__ __forceinline__ float bf2f(unsigned short h) {
    unsigned int u = ((unsigned int)h) << 16;
    return __builtin_bit_cast(float, u);
}

// ---------------------------------------------------------------------------
// K1: fused prep.  Blocks 0..1023: transpose input_feat -> fT[b][pix][c] bf16.
//     Block 1024: fvec + bias2.  Blocks 1025..1104: wkpack (conv A-operand).
// ---------------------------------------------------------------------------
__global__ __launch_bounds__(256) void prep_all_kernel(
        const float* __restrict__ input_feat,
        const float* __restrict__ c1w, const float* __restrict__ fea,
        const float* __restrict__ c2w, const float* __restrict__ bias,
        const float* __restrict__ com_w,
        unsigned short* __restrict__ fT, float* __restrict__ fvec,
        float* __restrict__ bias2, unsigned short* __restrict__ wk2) {
    int id = blockIdx.x, tid = threadIdx.x;
    if (id < 1024) {
        __shared__ float lt[64*65];
        int b = id >> 8;
        int px0 = (id & 255) * 64;
        const float* src = input_feat + (size_t)b*CIN*HW + px0;
        for (int i = tid; i < 4096; i += 256) {
            int c = i >> 6, px = i & 63;
            lt[c*65 + px] = src[(size_t)c*HW + px];
        }
        __syncthreads();
        int q = tid & 3, px = tid >> 2;     // px 0..63, q = 16-ch quarter
        unsigned short* dst = fT + ((size_t)b*HW + px0 + px)*64 + q*16;
        #pragma unroll
        for (int s = 0; s < 2; ++s) {
            short8 pk;
            #pragma unroll
            for (int j = 0; j < 8; ++j)
                pk[j] = (short)f2bf(lt[(q*16 + s*8 + j)*65 + px]);
            *(short8*)(dst + s*8) = pk;
        }
    } else if (id == 1024) {
        int b = tid >> 6, c = tid & 63;
        float s = 0.f;
        for (int i = 0; i < 4*CIN; ++i) s += c1w[c*(4*CIN) + i] * fea[b*(4*CIN) + i];
        fvec[tid] = s;
        if (tid < COUT) {
            float s2 = 0.f;
            for (int o = 0; o < COUT; ++o) s2 += c2w[tid*COUT + o] * bias[o];
            bias2[tid] = s2;
        }
    } else {
        int i = (id - 1025)*256 + tid;      // < 20480
        int k = i & 31, oc = (i >> 5) & 31;
        int cc5 = i >> 10;                  // cg*5 + chunk
        int cg = cc5 / 5, ch = cc5 % 5;
        int tap = ch*2 + (k >> 4);
        int c = cg*16 + (k & 15);
        float v = 0.f;
        if (tap < 9 && oc < 27) v = com_w[((size_t)oc*64 + c)*9 + tap];
        wk2[i] = f2bf(v);
    }
}

// ---------------------------------------------------------------------------
// K2: fused conv_off (MFMA, NO atomics) + w2 pack.
//     Blocks 0..511: conv.  z=(b, mh=oc-half); 16x16 px tile; all 64 in-ch
//     staged as 4 LDS tile passes; om = acc + com_b written directly.
//     Blocks 512..1087: W2b[b][p][o2][c] bf16 (MFMA A layout).
// ---------------------------------------------------------------------------
__global__ __launch_bounds__(256) void conv_w2_kernel(
        const float* __restrict__ inter,
        const unsigned short* __restrict__ wk2,
        const float* __restrict__ com_b,
        const float* __restrict__ weight,
        const float* __restrict__ c2w,
        const float* __restrict__ fvec,
        float* __restrict__ om, unsigned short* __restrict__ w2b) {
    __shared__ __align__(16) float smemf[4416];   // 17.7 KB union
    int id = blockIdx.x, tid = threadIdx.x;
    if (id < 512) {
        unsigned short* til = (unsigned short*)smemf;   // [325][24] bf16
        int bz = id >> 6;
        int b = bz >> 1, mh = bz & 1;
        int by = (id >> 3) & 7, bx = id & 7;
        int x0 = bx*16, y0 = by*16;
        int lane = tid & 63, wv = tid >> 6;
        int nn = lane & 15, qq = lane >> 4;

        f32x4 acc[4];
        #pragma unroll
        for (int nt = 0; nt < 4; ++nt)
            #pragma unroll
            for (int j = 0; j < 4; ++j) acc[nt][j] = 0.f;

        for (int cg = 0; cg < 4; ++cg) {
            __syncthreads();
            const float* I = inter + ((size_t)(b*CIN + cg*16))*HW;
            for (int i = tid; i < 16*324; i += 256) {
                int cl = i / 324, px = i % 324;
                int r = px / 18, cc = px % 18;
                int gy = y0 + r - 1, gx = x0 + cc - 1;
                float v = 0.f;
                if (gy >= 0 && gy < HH && gx >= 0 && gx < WW)
                    v = I[(size_t)cl*HW + gy*WW + gx];
                til[px*24 + cl] = f2bf(v);
            }
            if (tid < 24) til[324*24 + tid] = 0;   // zero row (tap-9 dummy)
            __syncthreads();

            short8 afr[5];
            #pragma unroll
            for (int ch = 0; ch < 5; ++ch)
                afr[ch] = *(const short8*)(wk2 +
                    (((size_t)(cg*5 + ch)*32 + mh*16 + nn)*32 + qq*8));

            #pragma unroll
            for (int nt = 0; nt < 4; ++nt) {
                int row = wv*4 + nt;
                #pragma unroll
                for (int ch = 0; ch < 5; ++ch) {
                    int tap = ch*2 + (qq >> 1);
                    int px_idx;
                    if (tap > 8) px_idx = 324;
                    else {
                        int ky = tap/3, kx = tap%3;
                        px_idx = (row + ky)*18 + (nn + kx);
                    }
                    short8 bfr = *(const short8*)(til + px_idx*24 + (qq&1)*8);
                    acc[nt] = __builtin_amdgcn_mfma_f32_16x16x32_bf16(
                                  afr[ch], bfr, acc[nt], 0, 0, 0);
                }
            }
        }

        float* op = om + (size_t)b*27*HW;
        #pragma unroll
        for (int nt = 0; nt < 4; ++nt) {
            int pix = (y0 + wv*4 + nt)*WW + x0 + nn;
            #pragma unroll
            for (int j = 0; j < 4; ++j) {
                int oc = mh*16 + qq*4 + j;
                if (oc < 27)
                    op[(size_t)oc*HW + pix] = acc[nt][j] + com_b[oc];
            }
        }
    } else {
        float* c2s  = smemf;            // [64*65]
        float* wcol = smemf + 64*65;    // [4*64]
        int wid = id - 512;
        int o2 = tid & 63, ci = tid >> 6;
        int bp = wid >> 4;
        int c_base = (wid & 15)*4;
        int p = bp % 9, b = bp / 9;
        int c = c_base + ci;
        for (int idx = tid; idx < 4096; idx += 256) {
            int o2r = idx >> 6, oc = idx & 63;
            c2s[oc*65 + o2r] = c2w[idx];
        }
        {
            int o = tid & 63, cw = tid >> 6;
            wcol[cw*64 + o] = weight[(o*CIN + (c_base + cw))*9 + p];
        }
        __syncthreads();
        float s = 0.f;
        #pragma unroll 8
        for (int o = 0; o < COUT; ++o) s += c2s[o*65 + o2] * wcol[ci*64 + o];
        w2b[(size_t)bp*4096 + o2*64 + c] = f2bf(s * fvec[b*CIN + c]);
    }
}

// ---------------------------------------------------------------------------
// K3: main DCN GEMM via bf16 MFMA, channel-last gather.
//     Lane (nn,qq) gathers its own B-frag channels as 4x16B corner loads per
//     ks (8 channels contiguous in fT) -> no LDS, no barriers, no cross-lane.
//     Wave owns a 16-px strip; grid (2,128,4) = 1024 blocks x 4 waves.
// ---------------------------------------------------------------------------
__global__ __launch_bounds__(256, 4) void dcn_main_kernel(
        const unsigned short* __restrict__ fT,
        const unsigned short* __restrict__ w2b,
        const float* __restrict__ bias2,
        const float* __restrict__ om,
        float* __restrict__ out) {
    int b = blockIdx.z;
    int t = threadIdx.x;
    int lane = t & 63, wv = t >> 6;
    int nn = lane & 15, qq = lane >> 4;
    int px0 = blockIdx.x*64 + wv*16;
    int y = blockIdx.y;
    int x = px0 + nn;
    int pix = y*WW + x;
    const unsigned short* Fb = fT + (size_t)b*HW*64;
    const float* omb = om + (size_t)b*27*HW;

    f32x4 acc[4];
    #pragma unroll
    for (int mt = 0; mt < 4; ++mt)
        #pragma unroll
        for (int j = 0; j < 4; ++j)
            acc[mt][j] = bias2[mt*16 + qq*4 + j];

    // prefetch p=0 om (com_b already folded in by conv kernel)
    float omy = omb[pix];
    float omx = omb[(size_t)HW + pix];
    float omm = omb[(size_t)18*HW + pix];

    for (int p = 0; p < 9; ++p) {
        // A-frag loads for this p (global, L2-hot)
        short8 afr[4][2];
        {
            size_t base = ((size_t)(b*9 + p)*64)*64;
            #pragma unroll
            for (int mt = 0; mt < 4; ++mt)
                #pragma unroll
                for (int ks = 0; ks < 2; ++ks)
                    afr[mt][ks] = *(const short8*)(w2b + base
                                    + (size_t)(mt*16 + nn)*64 + ks*32 + qq*8);
        }

        // bilinear corner weights for my pixel
        float dy = omy, dx = omx, ml = omm;
        float mv = 1.f / (1.f + expf(-ml));
        float ysv = (float)(y - 1 + p/3) + dy;
        float xsv = (float)(x - 1 + p%3) + dx;
        float y0f = floorf(ysv), x0f = floorf(xsv);
        float ly = ysv - y0f, lx = xsv - x0f;
        int y0 = (int)y0f, x0i = (int)x0f;
        int y1 = y0 + 1, x1 = x0i + 1;
        float vy0 = (y0 >= 0 && y0 < HH) ? 1.f : 0.f;
        float vy1 = (y1 >= 0 && y1 < HH) ? 1.f : 0.f;
        float vx0 = (x0i >= 0 && x0i < WW) ? 1.f : 0.f;
        float vx1 = (x1 >= 0 && x1 < WW) ? 1.f : 0.f;
        float w00 = (1.f-ly)*(1.f-lx)*mv * vy0*vx0;
        float w01 = (1.f-ly)*lx      *mv * vy0*vx1;
        float w10 = ly      *(1.f-lx)*mv * vy1*vx0;
        float w11 = ly      *lx      *mv * vy1*vx1;
        int y0c = min(max(y0,0),HH-1), y1c = min(max(y1,0),HH-1);
        int x0c = min(max(x0i,0),WW-1), x1c = min(max(x1,0),WW-1);
        int i00 = y0c*WW + x0c, i01 = y0c*WW + x1c;
        int i10 = y1c*WW + x0c, i11 = y1c*WW + x1c;

        // prefetch next p's om
        if (p < 8) {
            omy = omb[(size_t)(2*p+2)*HW + pix];
            omx = omb[(size_t)(2*p+3)*HW + pix];
            omm = omb[(size_t)(19+p )*HW + pix];
        }

        // gather: per ks, 4 corner short8 loads (8 contiguous channels each)
        short8 bfr[2];
        #pragma unroll
        for (int ks = 0; ks < 2; ++ks) {
            int co = ks*32 + qq*8;
            short8 c00 = *(const short8*)(Fb + (size_t)i00*64 + co);
            short8 c01 = *(const short8*)(Fb + (size_t)i01*64 + co);
            short8 c10 = *(const short8*)(Fb + (size_t)i10*64 + co);
            short8 c11 = *(const short8*)(Fb + (size_t)i11*64 + co);
            short8 pk;
            #pragma unroll
            for (int j = 0; j < 8; ++j) {
                float v = w00*bf2f((unsigned short)c00[j])
                        + w01*bf2f((unsigned short)c01[j])
                        + w10*bf2f((unsigned short)c10[j])
                        + w11*bf2f((unsigned short)c11[j]);
                pk[j] = (short)f2bf(v);
            }
            bfr[ks] = pk;
        }

        // MFMA: B[k=ks*32+qq*8+j][n=nn]
        #pragma unroll
        for (int ks = 0; ks < 2; ++ks)
            #pragma unroll
            for (int mt = 0; mt < 4; ++mt)
                acc[mt] = __builtin_amdgcn_mfma_f32_16x16x32_bf16(
                              afr[mt][ks], bfr[ks], acc[mt], 0, 0, 0);
    }

    // epilogue: D[m=qq*4+j][n=nn]
    float* outp = out + (size_t)b*COUT*HW + (size_t)y*WW + px0 + nn;
    #pragma unroll
    for (int mt = 0; mt < 4; ++mt)
        #pragma unroll
        for (int j = 0; j < 4; ++j)
            outp[(size_t)(mt*16 + qq*4 + j)*HW] = acc[mt][j];
}

// ---------------------------------------------------------------------------
extern "C" void kernel_launch(void* const* d_in, const int* in_sizes, int n_in,
                              void* d_out, int out_size, void* d_ws, size_t ws_size,
                              hipStream_t stream) {
    const float* input_feat = (const float*)d_in[0];
    const float* inter      = (const float*)d_in[1];
    const float* fea        = (const float*)d_in[2];
    const float* weight     = (const float*)d_in[3];
    const float* bias       = (const float*)d_in[4];
    const float* com_w      = (const float*)d_in[5];
    const float* com_b      = (const float*)d_in[6];
    const float* c1w        = (const float*)d_in[7];
    const float* c2w        = (const float*)d_in[8];
    float* out = (float*)d_out;

    // workspace layout (floats); total ~15.8 MB
    float* ws    = (float*)d_ws;
    float* fvec  = ws;                                     // 256
    float* bias2 = ws + 256;                               // 64 (pad to 512)
    unsigned short* w2b = (unsigned short*)(ws + 512);     // 147456 ushort
    float* om    = ws + 512 + 73728;                       // 1769472 floats
    unsigned short* wk2 = (unsigned short*)(om + 1769472); // 20480 ushort
    unsigned short* fT  = wk2 + 20480;                     // 4194304 ushort

    prep_all_kernel<<<1105, 256, 0, stream>>>(input_feat, c1w, fea, c2w, bias,
                                              com_w, fT, fvec, bias2, wk2);
    conv_w2_kernel<<<1088, 256, 0, stream>>>(inter, wk2, com_b, weight, c2w,
                                             fvec, om, w2b);
    dcn_main_kernel<<<dim3(2,128,4), 256, 0, stream>>>(fT, w2b, bias2, om, out);
}

// Round 9
// 194.273 us; speedup vs baseline: 2.4355x; 1.1619x over previous
//
#include <hip/hip_runtime.h>
#include <math.h>

// Problem constants
#define BB 4
#define CIN 64
#define COUT 64
#define HH 128
#define WW 128
#define HW (HH*WW)

typedef __attribute__((ext_vector_type(8))) short short8;   // 8 bf16 = 4 VGPRs
typedef __attribute__((ext_vector_type(4))) float f32x4;
typedef __attribute__((ext_vector_type(4))) unsigned int uint4v;

static __device__ __forceinline__ unsigned short f2bf(float f) {
    unsigned int u = __builtin_bit_cast(unsigned int, f);
    u += 0x7fffu + ((u >> 16) & 1u);          // round-to-nearest-even
    return (unsigned short)(u >> 16);
}
static __device__ __forceinline__ float bf2f(unsigned short h) {
    unsigned int u = ((unsigned int)h) << 16;
    return __builtin_bit_cast(float, u);
}

// ---------------------------------------------------------------------------
// K1: fused prep.  Blocks [0,nT): bf16 channel-last transpose (input_feat->fT,
//     and if big path, inter->iT).  Block nT: fvec+bias2.  Last 80: wkpack.
// ---------------------------------------------------------------------------
__global__ __launch_bounds__(256) void prep_all_kernel(
        const float* __restrict__ input_feat, const float* __restrict__ inter,
        const float* __restrict__ c1w, const float* __restrict__ fea,
        const float* __restrict__ c2w, const float* __restrict__ bias,
        const float* __restrict__ com_w,
        unsigned short* __restrict__ fT, unsigned short* __restrict__ iT,
        float* __restrict__ fvec, float* __restrict__ bias2,
        unsigned short* __restrict__ wk2) {
    int id = blockIdx.x, tid = threadIdx.x;
    int nT = gridDim.x - 81;
    if (id < nT) {
        __shared__ float lt[64*65];
        const float* srcb = (id < 1024) ? input_feat : inter;
        unsigned short* dstb = (id < 1024) ? fT : iT;
        int tb = (id < 1024) ? id : id - 1024;
        int b = tb >> 8;
        int px0 = (tb & 255) * 64;
        const float* src = srcb + (size_t)b*CIN*HW + px0;
        for (int i = tid; i < 4096; i += 256) {
            int c = i >> 6, px = i & 63;
            lt[c*65 + px] = src[(size_t)c*HW + px];
        }
        __syncthreads();
        int q = tid & 3, px = tid >> 2;     // px 0..63, q = 16-ch quarter
        unsigned short* dst = dstb + ((size_t)b*HW + px0 + px)*64 + q*16;
        #pragma unroll
        for (int s = 0; s < 2; ++s) {
            short8 pk;
            #pragma unroll
            for (int j = 0; j < 8; ++j)
                pk[j] = (short)f2bf(lt[(q*16 + s*8 + j)*65 + px]);
            *(short8*)(dst + s*8) = pk;
        }
    } else if (id == nT) {
        int b = tid >> 6, c = tid & 63;
        float s = 0.f;
        for (int i = 0; i < 4*CIN; ++i) s += c1w[c*(4*CIN) + i] * fea[b*(4*CIN) + i];
        fvec[tid] = s;
        if (tid < COUT) {
            float s2 = 0.f;
            for (int o = 0; o < COUT; ++o) s2 += c2w[tid*COUT + o] * bias[o];
            bias2[tid] = s2;
        }
    } else {
        int i = (id - nT - 1)*256 + tid;    // < 20480
        int k = i & 31, oc = (i >> 5) & 31;
        int cc5 = i >> 10;                  // cg*5 + chunk
        int cg = cc5 / 5, ch = cc5 % 5;
        int tap = ch*2 + (k >> 4);
        int c = cg*16 + (k & 15);
        float v = 0.f;
        if (tap < 9 && oc < 27) v = com_w[((size_t)oc*64 + c)*9 + tap];
        wk2[i] = f2bf(v);
    }
}

// ---------------------------------------------------------------------------
// w2 body (shared by both conv_w2 variants): W2b[b][p][o2][c] bf16 A-layout.
// ---------------------------------------------------------------------------
static __device__ __forceinline__ void w2_body(
        int wid, int tid, const float* __restrict__ weight,
        const float* __restrict__ c2w, const float* __restrict__ fvec,
        unsigned short* __restrict__ w2b, float* c2s, float* wcol) {
    int o2 = tid & 63, ci = tid >> 6;
    int bp = wid >> 4;
    int c_base = (wid & 15)*4;
    int p = bp % 9, b = bp / 9;
    int c = c_base + ci;
    for (int idx = tid; idx < 4096; idx += 256) {
        int o2r = idx >> 6, oc = idx & 63;
        c2s[oc*65 + o2r] = c2w[idx];
    }
    {
        int o = tid & 63, cw = tid >> 6;
        wcol[cw*64 + o] = weight[(o*CIN + (c_base + cw))*9 + p];
    }
    __syncthreads();
    float s = 0.f;
    #pragma unroll 8
    for (int o = 0; o < COUT; ++o) s += c2s[o*65 + o2] * wcol[ci*64 + o];
    w2b[(size_t)bp*4096 + o2*64 + c] = f2bf(s * fvec[b*CIN + c]);
}

// ---------------------------------------------------------------------------
// K2-fast: conv via register MFMA from channel-last iT (zero LDS, no barriers)
//     Blocks 0..511: conv, grid-encoded (b, oc-half, by, bx). 16x16 px tile.
//     Blocks 512..1087: w2 pack.
// ---------------------------------------------------------------------------
__global__ __launch_bounds__(256) void conv_w2_fast_kernel(
        const unsigned short* __restrict__ iT,
        const unsigned short* __restrict__ wk2,
        const float* __restrict__ com_b,
        const float* __restrict__ weight,
        const float* __restrict__ c2w,
        const float* __restrict__ fvec,
        float* __restrict__ om, unsigned short* __restrict__ w2b) {
    int id = blockIdx.x, tid = threadIdx.x;
    if (id < 512) {
        // taps: even (qq<2): 0,2,4,6,8 ; odd (qq>=2): 1,3,5,7,(9=dummy)
        const int KYE[5] = {0,0,1,2,2}, KXE[5] = {0,2,1,0,2};
        const int KYO[5] = {0,1,1,2,0}, KXO[5] = {1,0,2,1,0};
        int bz = id >> 6;                 // b*2 + mh
        int b = bz >> 1, mh = bz & 1;
        int by = (id >> 3) & 7, bx = id & 7;
        int x0 = bx*16, y0 = by*16;
        int lane = tid & 63, wv = tid >> 6;
        int nn = lane & 15, qq = lane >> 4;
        int qq1 = qq >> 1, qh = qq & 1;
        const unsigned short* iTb = iT + (size_t)b*HW*64;

        f32x4 acc[4];
        #pragma unroll
        for (int nt = 0; nt < 4; ++nt)
            #pragma unroll
            for (int j = 0; j < 4; ++j) acc[nt][j] = 0.f;

        #pragma unroll
        for (int cg = 0; cg < 4; ++cg) {
            short8 afr[5];
            #pragma unroll
            for (int ch = 0; ch < 5; ++ch)
                afr[ch] = *(const short8*)(wk2 +
                    (((size_t)(cg*5 + ch)*32 + mh*16 + nn)*32 + qq*8));
            #pragma unroll
            for (int ch = 0; ch < 5; ++ch) {
                int ky = qq1 ? KYO[ch] : KYE[ch];
                int kx = qq1 ? KXO[ch] : KXE[ch];
                bool tv = !(ch == 4 && qq1);
                int gx = x0 + nn + kx - 1;
                bool vx = tv && (gx >= 0) && (gx < WW);
                #pragma unroll
                for (int nt = 0; nt < 4; ++nt) {
                    int gy = y0 + wv*4 + nt + ky - 1;
                    bool ok = vx && (gy >= 0) && (gy < HH);
                    short8 bv = {0,0,0,0,0,0,0,0};
                    if (ok) bv = *(const short8*)(iTb +
                                    (size_t)(gy*WW + gx)*64 + cg*16 + qh*8);
                    acc[nt] = __builtin_amdgcn_mfma_f32_16x16x32_bf16(
                                  afr[ch], bv, acc[nt], 0, 0, 0);
                }
            }
        }

        float* op = om + (size_t)b*27*HW;
        #pragma unroll
        for (int nt = 0; nt < 4; ++nt) {
            int pix = (y0 + wv*4 + nt)*WW + x0 + nn;
            #pragma unroll
            for (int j = 0; j < 4; ++j) {
                int oc = mh*16 + qq*4 + j;
                if (oc < 27)
                    op[(size_t)oc*HW + pix] = acc[nt][j] + com_b[oc];
            }
        }
    } else {
        __shared__ float c2s[64*65];
        __shared__ float wcol[4*64];
        w2_body(id - 512, tid, weight, c2w, fvec, w2b, c2s, wcol);
    }
}

// ---------------------------------------------------------------------------
// K2-fallback: round-7 LDS-tile conv (used when ws too small for iT).
// ---------------------------------------------------------------------------
__global__ __launch_bounds__(256) void conv_w2_lds_kernel(
        const float* __restrict__ inter,
        const unsigned short* __restrict__ wk2,
        const float* __restrict__ com_b,
        const float* __restrict__ weight,
        const float* __restrict__ c2w,
        const float* __restrict__ fvec,
        float* __restrict__ om, unsigned short* __restrict__ w2b) {
    __shared__ __align__(16) float smemf[4416];
    int id = blockIdx.x, tid = threadIdx.x;
    if (id < 512) {
        unsigned short* til = (unsigned short*)smemf;   // [325][24]
        int bz = id >> 6;
        int b = bz >> 1, mh = bz & 1;
        int by = (id >> 3) & 7, bx = id & 7;
        int x0 = bx*16, y0 = by*16;
        int lane = tid & 63, wv = tid >> 6;
        int nn = lane & 15, qq = lane >> 4;

        f32x4 acc[4];
        #pragma unroll
        for (int nt = 0; nt < 4; ++nt)
            #pragma unroll
            for (int j = 0; j < 4; ++j) acc[nt][j] = 0.f;

        for (int cg = 0; cg < 4; ++cg) {
            __syncthreads();
            const float* I = inter + ((size_t)(b*CIN + cg*16))*HW;
            for (int i = tid; i < 16*324; i += 256) {
                int cl = i / 324, px = i % 324;
                int r = px / 18, cc = px % 18;
                int gy = y0 + r - 1, gx = x0 + cc - 1;
                float v = 0.f;
                if (gy >= 0 && gy < HH && gx >= 0 && gx < WW)
                    v = I[(size_t)cl*HW + gy*WW + gx];
                til[px*24 + cl] = f2bf(v);
            }
            if (tid < 24) til[324*24 + tid] = 0;
            __syncthreads();

            short8 afr[5];
            #pragma unroll
            for (int ch = 0; ch < 5; ++ch)
                afr[ch] = *(const short8*)(wk2 +
                    (((size_t)(cg*5 + ch)*32 + mh*16 + nn)*32 + qq*8));
            #pragma unroll
            for (int nt = 0; nt < 4; ++nt) {
                int row = wv*4 + nt;
                #pragma unroll
                for (int ch = 0; ch < 5; ++ch) {
                    int tap = ch*2 + (qq >> 1);
                    int px_idx;
                    if (tap > 8) px_idx = 324;
                    else {
                        int ky = tap/3, kx = tap%3;
                        px_idx = (row + ky)*18 + (nn + kx);
                    }
                    short8 bfr = *(const short8*)(til + px_idx*24 + (qq&1)*8);
                    acc[nt] = __builtin_amdgcn_mfma_f32_16x16x32_bf16(
                                  afr[ch], bfr, acc[nt], 0, 0, 0);
                }
            }
        }

        float* op = om + (size_t)b*27*HW;
        #pragma unroll
        for (int nt = 0; nt < 4; ++nt) {
            int pix = (y0 + wv*4 + nt)*WW + x0 + nn;
            #pragma unroll
            for (int j = 0; j < 4; ++j) {
                int oc = mh*16 + qq*4 + j;
                if (oc < 27)
                    op[(size_t)oc*HW + pix] = acc[nt][j] + com_b[oc];
            }
        }
    } else {
        float* c2s  = smemf;
        float* wcol = smemf + 64*65;
        w2_body(id - 512, tid, weight, c2w, fvec, w2b, c2s, wcol);
    }
}

// ---------------------------------------------------------------------------
// bilinear coord + gather-issue helper for dcn (kp is compile-time constant)
// ---------------------------------------------------------------------------
static __device__ __forceinline__ void bilin_issue(
        int y, int x, int kp, float oy, float ox, float omsk,
        const unsigned short* __restrict__ Fb, int qq,
        short8* dst, float* wdst) {
    float mv = 1.f / (1.f + expf(-omsk));
    float ysv = (float)(y - 1 + kp/3) + oy;
    float xsv = (float)(x - 1 + kp%3) + ox;
    float y0f = floorf(ysv), x0f = floorf(xsv);
    float ly = ysv - y0f, lx = xsv - x0f;
    int y0 = (int)y0f, x0i = (int)x0f;
    int y1 = y0 + 1, x1 = x0i + 1;
    float vy0 = (y0 >= 0 && y0 < HH) ? 1.f : 0.f;
    float vy1 = (y1 >= 0 && y1 < HH) ? 1.f : 0.f;
    float vx0 = (x0i >= 0 && x0i < WW) ? 1.f : 0.f;
    float vx1 = (x1 >= 0 && x1 < WW) ? 1.f : 0.f;
    wdst[0] = (1.f-ly)*(1.f-lx)*mv * vy0*vx0;
    wdst[1] = (1.f-ly)*lx      *mv * vy0*vx1;
    wdst[2] = ly      *(1.f-lx)*mv * vy1*vx0;
    wdst[3] = ly      *lx      *mv * vy1*vx1;
    int y0c = min(max(y0,0),HH-1), y1c = min(max(y1,0),HH-1);
    int x0c = min(max(x0i,0),WW-1), x1c = min(max(x1,0),WW-1);
    int i00 = y0c*WW + x0c, i01 = y0c*WW + x1c;
    int i10 = y1c*WW + x0c, i11 = y1c*WW + x1c;
    #pragma unroll
    for (int ks = 0; ks < 2; ++ks) {
        int co = ks*32 + qq*8;
        dst[ks*4+0] = *(const short8*)(Fb + (size_t)i00*64 + co);
        dst[ks*4+1] = *(const short8*)(Fb + (size_t)i01*64 + co);
        dst[ks*4+2] = *(const short8*)(Fb + (size_t)i10*64 + co);
        dst[ks*4+3] = *(const short8*)(Fb + (size_t)i11*64 + co);
    }
}

// ---------------------------------------------------------------------------
// K3: main DCN GEMM, bf16 MFMA, software-pipelined gathers (depth 1).
//     Fully unrolled p-loop; double-buffered corner regs; no LDS/barriers.
// ---------------------------------------------------------------------------
__global__ __launch_bounds__(256, 4) void dcn_main_kernel(
        const unsigned short* __restrict__ fT,
        const unsigned short* __restrict__ w2b,
        const float* __restrict__ bias2,
        const float* __restrict__ om,
        float* __restrict__ out) {
    int b = blockIdx.z;
    int t = threadIdx.x;
    int lane = t & 63, wv = t >> 6;
    int nn = lane & 15, qq = lane >> 4;
    int px0 = blockIdx.x*64 + wv*16;
    int y = blockIdx.y;
    int x = px0 + nn;
    int pix = y*WW + x;
    const unsigned short* Fb = fT + (size_t)b*HW*64;
    const float* omb = om + (size_t)b*27*HW;
    const unsigned short* w2p = w2b + (size_t)(b*9)*4096;

    f32x4 acc[4];
    #pragma unroll
    for (int mt = 0; mt < 4; ++mt)
        #pragma unroll
        for (int j = 0; j < 4; ++j)
            acc[mt][j] = bias2[mt*16 + qq*4 + j];

    short8 cb[2][8];
    float  cw[2][4];

    // prologue: om p=0 -> issue gathers p=0; load om p=1
    float omy = omb[pix];
    float omx = omb[(size_t)HW + pix];
    float omm = omb[(size_t)18*HW + pix];
    bilin_issue(y, x, 0, omy, omx, omm, Fb, qq, cb[0], cw[0]);
    omy = omb[(size_t)2*HW + pix];
    omx = omb[(size_t)3*HW + pix];
    omm = omb[(size_t)19*HW + pix];

    #pragma unroll
    for (int p = 0; p < 9; ++p) {
        const int cur = p & 1, nxt = cur ^ 1;

        // issue gathers for p+1 (overlaps pack+MFMA of p)
        if (p < 8) {
            bilin_issue(y, x, p+1, omy, omx, omm, Fb, qq, cb[nxt], cw[nxt]);
            if (p < 7) {
                omy = omb[(size_t)(2*p+4)*HW + pix];
                omx = omb[(size_t)(2*p+5)*HW + pix];
                omm = omb[(size_t)(20+p )*HW + pix];
            }
        }

        // A-frags for p (L2-hot)
        short8 afr[4][2];
        #pragma unroll
        for (int mt = 0; mt < 4; ++mt)
            #pragma unroll
            for (int ks = 0; ks < 2; ++ks)
                afr[mt][ks] = *(const short8*)(w2p + (size_t)p*4096
                                + (size_t)(mt*16 + nn)*64 + ks*32 + qq*8);

        // pack p's corners (loads issued one iteration ago)
        short8 bfr[2];
        #pragma unroll
        for (int ks = 0; ks < 2; ++ks) {
            unsigned int pw[4];
            #pragma unroll
            for (int jp = 0; jp < 4; ++jp) {
                float v0 = cw[cur][0]*bf2f((unsigned short)cb[cur][ks*4+0][2*jp])
                         + cw[cur][1]*bf2f((unsigned short)cb[cur][ks*4+1][2*jp])
                         + cw[cur][2]*bf2f((unsigned short)cb[cur][ks*4+2][2*jp])
                         + cw[cur][3]*bf2f((unsigned short)cb[cur][ks*4+3][2*jp]);
                float v1 = cw[cur][0]*bf2f((unsigned short)cb[cur][ks*4+0][2*jp+1])
                         + cw[cur][1]*bf2f((unsigned short)cb[cur][ks*4+1][2*jp+1])
                         + cw[cur][2]*bf2f((unsigned short)cb[cur][ks*4+2][2*jp+1])
                         + cw[cur][3]*bf2f((unsigned short)cb[cur][ks*4+3][2*jp+1]);
                pw[jp] = (unsigned int)f2bf(v0) | ((unsigned int)f2bf(v1) << 16);
            }
            uint4v u4 = {pw[0], pw[1], pw[2], pw[3]};
            bfr[ks] = __builtin_bit_cast(short8, u4);
        }

        // MFMA
        #pragma unroll
        for (int ks = 0; ks < 2; ++ks)
            #pragma unroll
            for (int mt = 0; mt < 4; ++mt)
                acc[mt] = __builtin_amdgcn_mfma_f32_16x16x32_bf16(
                              afr[mt][ks], bfr[ks], acc[mt], 0, 0, 0);
    }

    // epilogue: D[m=qq*4+j][n=nn]
    float* outp = out + (size_t)b*COUT*HW + (size_t)y*WW + px0 + nn;
    #pragma unroll
    for (int mt = 0; mt < 4; ++mt)
        #pragma unroll
        for (int j = 0; j < 4; ++j)
            outp[(size_t)(mt*16 + qq*4 + j)*HW] = acc[mt][j];
}

// ---------------------------------------------------------------------------
extern "C" void kernel_launch(void* const* d_in, const int* in_sizes, int n_in,
                              void* d_out, int out_size, void* d_ws, size_t ws_size,
                              hipStream_t stream) {
    const float* input_feat = (const float*)d_in[0];
    const float* inter      = (const float*)d_in[1];
    const float* fea        = (const float*)d_in[2];
    const float* weight     = (const float*)d_in[3];
    const float* bias       = (const float*)d_in[4];
    const float* com_w      = (const float*)d_in[5];
    const float* com_b      = (const float*)d_in[6];
    const float* c1w        = (const float*)d_in[7];
    const float* c2w        = (const float*)d_in[8];
    float* out = (float*)d_out;

    // workspace layout (small prefix = round-7 proven footprint; iT appended)
    float* ws    = (float*)d_ws;
    float* fvec  = ws;                                     // 256
    float* bias2 = ws + 256;                               // 64 (pad to 512)
    unsigned short* w2b = (unsigned short*)(ws + 512);     // 147456 us
    float* om    = ws + 512 + 73728;                       // 1769472 f
    unsigned short* wk2 = (unsigned short*)(om + 1769472); // 20480 us
    unsigned short* fT  = wk2 + 20480;                     // 4194304 us
    unsigned short* iT  = fT + 4194304;                    // 4194304 us (big only)
    size_t need_big = ((size_t)(512 + 73728 + 1769472 + 10240 + 2097152 + 2097152))*4;
    bool big = ws_size >= need_big;

    if (big) {
        prep_all_kernel<<<2129, 256, 0, stream>>>(input_feat, inter, c1w, fea,
                c2w, bias, com_w, fT, iT, fvec, bias2, wk2);
        conv_w2_fast_kernel<<<1088, 256, 0, stream>>>(iT, wk2, com_b, weight,
                c2w, fvec, om, w2b);
    } else {
        prep_all_kernel<<<1105, 256, 0, stream>>>(input_feat, inter, c1w, fea,
                c2w, bias, com_w, fT, iT, fvec, bias2, wk2);
        conv_w2_lds_kernel<<<1088, 256, 0, stream>>>(inter, wk2, com_b, weight,
                c2w, fvec, om, w2b);
    }
    dcn_main_kernel<<<dim3(2,128,4), 256, 0, stream>>>(fT, w2b, bias2, om, out);
}